// Round 2
// baseline (1228.801 us; speedup 1.0000x reference)
//
#include <hip/hip_runtime.h>
#include <hip/hip_bf16.h>

typedef unsigned short ushort_t;

// bf16 (as raw u16) -> f32
__device__ __forceinline__ float bf2f(ushort_t u) {
    unsigned int x = ((unsigned int)u) << 16;
    float f;
    __builtin_memcpy(&f, &x, 4);
    return f;
}
// f32 -> bf16 (RTNE)
__device__ __forceinline__ ushort_t f2bf(float f) {
    unsigned int x;
    __builtin_memcpy(&x, &f, 4);
    x += 0x7fff + ((x >> 16) & 1);
    return (ushort_t)(x >> 16);
}

constexpr int E  = 1024;
constexpr int Hd = 64;
constexpr int S  = 2048;
constexpr int ROWS = 8 * 2048; // B*S = 16384
constexpr int RPB = 16;        // rows per block in projection

// q/k/v projection: one thread per (row, h); 16 rows per 1024-thread block.
// Inputs are FP32 (per reference). x row element is wave-uniform (h = lane)
// -> broadcast load; W[e*64+h] is lane-contiguous -> coalesced 256B/wave.
// q/k/v staged as bf16 in workspace.
__global__ __launch_bounds__(1024)
void proj_kernel(const float* __restrict__ x,
                 const float* __restrict__ Wk,
                 const float* __restrict__ Wq,
                 const float* __restrict__ Wv,
                 ushort_t* __restrict__ qo,
                 ushort_t* __restrict__ ko,
                 ushort_t* __restrict__ vo)
{
    const int h  = threadIdx.x & 63;
    const int rl = threadIdx.x >> 6;
    const size_t row = (size_t)blockIdx.x * RPB + rl;
    const float* xr = x + row * E;

    float aq = 0.f, ak = 0.f, av = 0.f;
    for (int e0 = 0; e0 < E; e0 += 4) {
        // 4 x values (16B wave-uniform broadcast load)
        float4 xp = *(const float4*)(xr + e0);
        int b0 = (e0 + 0) * Hd + h;
        int b1 = (e0 + 1) * Hd + h;
        int b2 = (e0 + 2) * Hd + h;
        int b3 = (e0 + 3) * Hd + h;
        aq += xp.x * Wq[b0]; ak += xp.x * Wk[b0]; av += xp.x * Wv[b0];
        aq += xp.y * Wq[b1]; ak += xp.y * Wk[b1]; av += xp.y * Wv[b1];
        aq += xp.z * Wq[b2]; ak += xp.z * Wk[b2]; av += xp.z * Wv[b2];
        aq += xp.w * Wq[b3]; ak += xp.w * Wk[b3]; av += xp.w * Wv[b3];
    }
    const size_t o = row * Hd + h;
    qo[o] = f2bf(aq);
    ko[o] = f2bf(ak);
    vo[o] = f2bf(av);
}

// Causal attention, one 256-thread block per query row. q/k/v are bf16
// (staged), output is FP32 (per reference).
__global__ __launch_bounds__(256)
void attn_kernel(const ushort_t* __restrict__ q,
                 const ushort_t* __restrict__ k,
                 const ushort_t* __restrict__ v,
                 float* __restrict__ out)
{
    const int row  = blockIdx.x;         // global row in [0, B*S)
    const int b    = row >> 11;          // S = 2048
    const int qi   = row & (S - 1);
    const int n    = qi + 1;             // number of visible keys
    const int tid  = threadIdx.x;
    const int lane = tid & 63;
    const int wid  = tid >> 6;

    __shared__ float sc[S];
    __shared__ float qs[Hd];
    __shared__ float rbuf[4];
    __shared__ float part[4][Hd];

    const ushort_t* kb = k + (size_t)b * S * Hd;
    const ushort_t* vb = v + (size_t)b * S * Hd;

    if (tid < Hd) qs[tid] = bf2f(q[(size_t)row * Hd + tid]);
    __syncthreads();

    // scores = (q . k_j) * H^-0.5
    float lmax = -1e30f;
    for (int j = tid; j < n; j += 256) {
        const ushort_t* kr = kb + (size_t)j * Hd;
        float acc = 0.f;
        #pragma unroll
        for (int c = 0; c < 8; ++c) {
            uint4 u = *(const uint4*)(kr + c * 8); // 8 bf16 = 16B
            acc += qs[c * 8 + 0] * bf2f((ushort_t)(u.x & 0xffff));
            acc += qs[c * 8 + 1] * bf2f((ushort_t)(u.x >> 16));
            acc += qs[c * 8 + 2] * bf2f((ushort_t)(u.y & 0xffff));
            acc += qs[c * 8 + 3] * bf2f((ushort_t)(u.y >> 16));
            acc += qs[c * 8 + 4] * bf2f((ushort_t)(u.z & 0xffff));
            acc += qs[c * 8 + 5] * bf2f((ushort_t)(u.z >> 16));
            acc += qs[c * 8 + 6] * bf2f((ushort_t)(u.w & 0xffff));
            acc += qs[c * 8 + 7] * bf2f((ushort_t)(u.w >> 16));
        }
        float s = acc * 0.125f; // 1/sqrt(64)
        sc[j] = s;
        lmax = fmaxf(lmax, s);
    }
    // block max
    #pragma unroll
    for (int o = 32; o > 0; o >>= 1) lmax = fmaxf(lmax, __shfl_down(lmax, o, 64));
    if (lane == 0) rbuf[wid] = lmax;
    __syncthreads();
    const float m = fmaxf(fmaxf(rbuf[0], rbuf[1]), fmaxf(rbuf[2], rbuf[3]));
    __syncthreads();

    // exp + block sum
    float lsum = 0.f;
    for (int j = tid; j < n; j += 256) {
        float p = __expf(sc[j] - m);
        sc[j] = p;
        lsum += p;
    }
    #pragma unroll
    for (int o = 32; o > 0; o >>= 1) lsum += __shfl_down(lsum, o, 64);
    if (lane == 0) rbuf[wid] = lsum;
    __syncthreads();
    const float l = rbuf[0] + rbuf[1] + rbuf[2] + rbuf[3];

    // out[h] = sum_j p_j * v[j,h] / l ; wave w handles j = w mod 4
    float acc = 0.f;
    for (int j = wid; j < n; j += 4) {
        acc += sc[j] * bf2f(vb[(size_t)j * Hd + lane]);
    }
    part[wid][lane] = acc;
    __syncthreads();
    if (tid < Hd) {
        float s = part[0][lane] + part[1][lane] + part[2][lane] + part[3][lane];
        out[(size_t)row * Hd + lane] = s / l;
    }
}

extern "C" void kernel_launch(void* const* d_in, const int* in_sizes, int n_in,
                              void* d_out, int out_size, void* d_ws, size_t ws_size,
                              hipStream_t stream) {
    const float* x  = (const float*)d_in[0];
    const float* Wk = (const float*)d_in[1];
    const float* Wq = (const float*)d_in[2];
    const float* Wv = (const float*)d_in[3];
    float* out = (float*)d_out;

    // workspace: q, k, v as bf16, each ROWS*Hd elements (6 MB total)
    ushort_t* qws = (ushort_t*)d_ws;
    ushort_t* kws = qws + (size_t)ROWS * Hd;
    ushort_t* vws = kws + (size_t)ROWS * Hd;

    proj_kernel<<<ROWS / RPB, 1024, 0, stream>>>(x, Wk, Wq, Wv, qws, kws, vws);
    attn_kernel<<<ROWS, 256, 0, stream>>>(qws, kws, vws, out);
}

// Round 3
// 267.731 us; speedup vs baseline: 4.5897x; 4.5897x over previous
//
#include <hip/hip_runtime.h>
#include <hip/hip_bf16.h>

typedef unsigned short ushort_t;
typedef __attribute__((ext_vector_type(8))) short short8;   // 8 bf16 (4 VGPRs)
typedef __attribute__((ext_vector_type(4))) float f32x4;    // 4 fp32 acc

__device__ __forceinline__ float bf2f(ushort_t u) {
    unsigned int x = ((unsigned int)u) << 16;
    float f; __builtin_memcpy(&f, &x, 4); return f;
}
__device__ __forceinline__ ushort_t f2bf(float f) {
    unsigned int x; __builtin_memcpy(&x, &f, 4);
    x += 0x7fff + ((x >> 16) & 1);
    return (ushort_t)(x >> 16);
}

constexpr int E  = 1024;
constexpr int Hd = 64;
constexpr int S  = 2048;
constexpr int ROWS = 8 * 2048;   // 16384
constexpr int NTOT = 192;        // Q|K|V output columns

// ---------------------------------------------------------------------------
// prep: WT[192][1024] bf16, rows 0-63 = Wq^T, 64-127 = Wk^T, 128-191 = Wv^T
__global__ __launch_bounds__(256)
void prep_wt(const float* __restrict__ Wk, const float* __restrict__ Wq,
             const float* __restrict__ Wv, ushort_t* __restrict__ WT)
{
    int idx = blockIdx.x * 256 + threadIdx.x;   // 192*1024 total
    int n = idx >> 10;                          // output row (0..191)
    int k = idx & 1023;
    const float* W = (n < 64) ? Wq : ((n < 128) ? Wk : Wv);
    int h = n & 63;
    WT[idx] = f2bf(W[k * Hd + h]);
}

// ---------------------------------------------------------------------------
// Projection GEMM: C[16384 x 192] = X[16384 x 1024] * WT^T, MFMA 16x16x32 bf16.
// Block = 256 thr (4 waves), 64 rows/block; wave w owns rows rb+16w..+15.
// q written pre-scaled by 1/8 (= Hd^-0.5).
__global__ __launch_bounds__(256)
void proj_mfma(const float* __restrict__ x, const ushort_t* __restrict__ WT,
               ushort_t* __restrict__ qo, ushort_t* __restrict__ ko,
               ushort_t* __restrict__ vo)
{
    const int w    = threadIdx.x >> 6;
    const int lane = threadIdx.x & 63;
    const int m    = lane & 15;      // A-row / C-col index
    const int g    = lane >> 4;      // k-group / C-row group
    const int rb   = blockIdx.x * 64;

    f32x4 acc[12];
    #pragma unroll
    for (int i = 0; i < 12; ++i) acc[i] = (f32x4){0.f, 0.f, 0.f, 0.f};

    const float* xr = x + (size_t)(rb + w * 16 + m) * E;

    for (int kt = 0; kt < E / 32; ++kt) {
        const int k0 = kt * 32 + g * 8;
        float4 xa = *(const float4*)(xr + k0);
        float4 xb = *(const float4*)(xr + k0 + 4);
        short8 a;
        a[0] = (short)f2bf(xa.x); a[1] = (short)f2bf(xa.y);
        a[2] = (short)f2bf(xa.z); a[3] = (short)f2bf(xa.w);
        a[4] = (short)f2bf(xb.x); a[5] = (short)f2bf(xb.y);
        a[6] = (short)f2bf(xb.z); a[7] = (short)f2bf(xb.w);
        #pragma unroll
        for (int nt = 0; nt < 12; ++nt) {
            short8 b = *(const short8*)(WT + (size_t)(nt * 16 + m) * E + k0);
            acc[nt] = __builtin_amdgcn_mfma_f32_16x16x32_bf16(a, b, acc[nt], 0, 0, 0);
        }
    }

    // Epilogue: C/D layout col = m, row = 4g + r
    const int orow = rb + w * 16 + g * 4;
    #pragma unroll
    for (int nt = 0; nt < 4; ++nt)
        #pragma unroll
        for (int r = 0; r < 4; ++r)
            qo[(size_t)(orow + r) * Hd + nt * 16 + m] = f2bf(acc[nt][r] * 0.125f);
    #pragma unroll
    for (int nt = 0; nt < 4; ++nt)
        #pragma unroll
        for (int r = 0; r < 4; ++r)
            ko[(size_t)(orow + r) * Hd + nt * 16 + m] = f2bf(acc[4 + nt][r]);
    #pragma unroll
    for (int nt = 0; nt < 4; ++nt)
        #pragma unroll
        for (int r = 0; r < 4; ++r)
            vo[(size_t)(orow + r) * Hd + nt * 16 + m] = f2bf(acc[8 + nt][r]);
}

// ---------------------------------------------------------------------------
// Flash attention: one block per 64-row q-tile (4 waves x 16 rows).
// q is pre-scaled by 1/8.
__global__ __launch_bounds__(256)
void attn_mfma(const ushort_t* __restrict__ q, const ushort_t* __restrict__ k,
               const ushort_t* __restrict__ v, float* __restrict__ out)
{
    const int qt    = blockIdx.x;
    const int grow0 = qt * 64;           // global row base
    const int batch = grow0 >> 11;
    const int qs0   = grow0 & (S - 1);   // seq position base (64-aligned)
    const ushort_t* kb = k + (size_t)batch * S * Hd;
    const ushort_t* vb = v + (size_t)batch * S * Hd;

    const int w    = threadIdx.x >> 6;
    const int lane = threadIdx.x & 63;
    const int m    = lane & 15;
    const int g    = lane >> 4;

    __shared__ alignas(16) ushort_t VT[Hd][72];       // [h][key], pad->72
    __shared__ alignas(16) ushort_t PL[4][16][72];    // per-wave P [row][key]

    // Q fragments: A[m][k] = q[grow0+16w+m][k], k split 0-31 / 32-63
    short8 qf0, qf1;
    {
        const ushort_t* qrow = q + (size_t)(grow0 + w * 16 + m) * Hd;
        qf0 = *(const short8*)(qrow + g * 8);
        qf1 = *(const short8*)(qrow + 32 + g * 8);
    }

    f32x4 o[4];
    #pragma unroll
    for (int i = 0; i < 4; ++i) o[i] = (f32x4){0.f, 0.f, 0.f, 0.f};
    float mrun[4] = {-INFINITY, -INFINITY, -INFINITY, -INFINITY};
    float lrun[4] = {0.f, 0.f, 0.f, 0.f};

    const int nkt = (qs0 >> 6) + 1;
    for (int kt = 0; kt < nkt; ++kt) {
        const int key0 = kt * 64;

        // ---- stage V^T tile: VT[h][key] = v[key0+key][h]
        {
            const int t  = threadIdx.x;
            const int kr = t >> 3;             // 0..31
            const int c8 = (t & 7) * 8;
            #pragma unroll
            for (int p = 0; p < 2; ++p) {
                const int key = kr + p * 32;
                uint4 u = *(const uint4*)(vb + (size_t)(key0 + key) * Hd + c8);
                VT[c8 + 0][key] = (ushort_t)(u.x & 0xffff);
                VT[c8 + 1][key] = (ushort_t)(u.x >> 16);
                VT[c8 + 2][key] = (ushort_t)(u.y & 0xffff);
                VT[c8 + 3][key] = (ushort_t)(u.y >> 16);
                VT[c8 + 4][key] = (ushort_t)(u.z & 0xffff);
                VT[c8 + 5][key] = (ushort_t)(u.z >> 16);
                VT[c8 + 6][key] = (ushort_t)(u.w & 0xffff);
                VT[c8 + 7][key] = (ushort_t)(u.w >> 16);
            }
        }
        __syncthreads();

        // ---- S = Q K^T (q pre-scaled)
        f32x4 s[4];
        #pragma unroll
        for (int i = 0; i < 4; ++i) s[i] = (f32x4){0.f, 0.f, 0.f, 0.f};
        #pragma unroll
        for (int nt = 0; nt < 4; ++nt) {
            const ushort_t* krow = kb + (size_t)(key0 + nt * 16 + m) * Hd;
            short8 b0 = *(const short8*)(krow + g * 8);
            short8 b1 = *(const short8*)(krow + 32 + g * 8);
            s[nt] = __builtin_amdgcn_mfma_f32_16x16x32_bf16(qf0, b0, s[nt], 0, 0, 0);
            s[nt] = __builtin_amdgcn_mfma_f32_16x16x32_bf16(qf1, b1, s[nt], 0, 0, 0);
        }

        // ---- causal mask (only the diagonal tile is partial)
        if (kt == nkt - 1) {
            const int rowg = qs0 + w * 16 + g * 4;
            #pragma unroll
            for (int nt = 0; nt < 4; ++nt) {
                const int keyg = key0 + nt * 16 + m;
                #pragma unroll
                for (int r = 0; r < 4; ++r)
                    if (keyg > rowg + r) s[nt][r] = -INFINITY;
            }
        }

        // ---- online softmax row stats (rows live across 16-lane groups)
        float mnew[4], alpha[4];
        #pragma unroll
        for (int r = 0; r < 4; ++r) {
            float t = fmaxf(fmaxf(s[0][r], s[1][r]), fmaxf(s[2][r], s[3][r]));
            #pragma unroll
            for (int d = 1; d < 16; d <<= 1) t = fmaxf(t, __shfl_xor(t, d, 64));
            mnew[r]  = fmaxf(mrun[r], t);
            alpha[r] = __expf(mrun[r] - mnew[r]);
            mrun[r]  = mnew[r];
        }
        #pragma unroll
        for (int nt = 0; nt < 4; ++nt)
            #pragma unroll
            for (int r = 0; r < 4; ++r)
                s[nt][r] = __expf(s[nt][r] - mnew[r]);
        #pragma unroll
        for (int r = 0; r < 4; ++r) {
            float t = s[0][r] + s[1][r] + s[2][r] + s[3][r];
            #pragma unroll
            for (int d = 1; d < 16; d <<= 1) t += __shfl_xor(t, d, 64);
            lrun[r] = lrun[r] * alpha[r] + t;
        }
        #pragma unroll
        for (int nt = 0; nt < 4; ++nt)
            #pragma unroll
            for (int r = 0; r < 4; ++r)
                o[nt][r] *= alpha[r];

        // ---- P -> per-wave LDS (C-layout scatter), then read A-layout
        #pragma unroll
        for (int nt = 0; nt < 4; ++nt)
            #pragma unroll
            for (int r = 0; r < 4; ++r)
                PL[w][g * 4 + r][nt * 16 + m] = f2bf(s[nt][r]);

        short8 pa0 = *(const short8*)&PL[w][m][g * 8];
        short8 pa1 = *(const short8*)&PL[w][m][32 + g * 8];

        // ---- O += P V  (B[k][n] = VT[nt*16+m][k])
        #pragma unroll
        for (int nt = 0; nt < 4; ++nt) {
            short8 vb0 = *(const short8*)&VT[nt * 16 + m][g * 8];
            short8 vb1 = *(const short8*)&VT[nt * 16 + m][32 + g * 8];
            o[nt] = __builtin_amdgcn_mfma_f32_16x16x32_bf16(pa0, vb0, o[nt], 0, 0, 0);
            o[nt] = __builtin_amdgcn_mfma_f32_16x16x32_bf16(pa1, vb1, o[nt], 0, 0, 0);
        }
        __syncthreads();   // protect VT before next iteration's staging
    }

    // ---- epilogue: out fp32, row = grow0+16w+4g+r, col = nt*16+m
    float inv[4];
    #pragma unroll
    for (int r = 0; r < 4; ++r) inv[r] = 1.f / lrun[r];
    const int orow = grow0 + w * 16 + g * 4;
    #pragma unroll
    for (int nt = 0; nt < 4; ++nt)
        #pragma unroll
        for (int r = 0; r < 4; ++r)
            out[(size_t)(orow + r) * Hd + nt * 16 + m] = o[nt][r] * inv[r];
}

// ---------------------------------------------------------------------------
extern "C" void kernel_launch(void* const* d_in, const int* in_sizes, int n_in,
                              void* d_out, int out_size, void* d_ws, size_t ws_size,
                              hipStream_t stream) {
    const float* x  = (const float*)d_in[0];
    const float* Wk = (const float*)d_in[1];
    const float* Wq = (const float*)d_in[2];
    const float* Wv = (const float*)d_in[3];
    float* out = (float*)d_out;

    ushort_t* qws = (ushort_t*)d_ws;                       // 16384*64 bf16
    ushort_t* kws = qws + (size_t)ROWS * Hd;
    ushort_t* vws = kws + (size_t)ROWS * Hd;
    ushort_t* WT  = vws + (size_t)ROWS * Hd;               // 192*1024 bf16

    prep_wt<<<(NTOT * E) / 256, 256, 0, stream>>>(Wk, Wq, Wv, WT);
    proj_mfma<<<ROWS / 64, 256, 0, stream>>>(x, WT, qws, kws, vws);
    attn_mfma<<<ROWS / 64, 256, 0, stream>>>(qws, kws, vws, out);
}

// Round 4
// 190.610 us; speedup vs baseline: 6.4467x; 1.4046x over previous
//
#include <hip/hip_runtime.h>
#include <hip/hip_bf16.h>

typedef unsigned short ushort_t;
typedef __attribute__((ext_vector_type(8))) short short8;   // 8 bf16 (4 VGPRs)
typedef __attribute__((ext_vector_type(4))) float f32x4;    // 4 fp32 acc

__device__ __forceinline__ float bf2f(ushort_t u) {
    unsigned int x = ((unsigned int)u) << 16;
    float f; __builtin_memcpy(&f, &x, 4); return f;
}
__device__ __forceinline__ ushort_t f2bf(float f) {
    unsigned int x; __builtin_memcpy(&x, &f, 4);
    x += 0x7fff + ((x >> 16) & 1);
    return (ushort_t)(x >> 16);
}

constexpr int E  = 1024;
constexpr int Hd = 64;
constexpr int S  = 2048;
constexpr int ROWS = 8 * 2048;   // 16384
constexpr int NTOT = 192;        // Q|K|V output columns

// ---------------------------------------------------------------------------
// prep: WT[192][1024] bf16, rows 0-63 = Wq^T, 64-127 = Wk^T, 128-191 = Wv^T
__global__ __launch_bounds__(256)
void prep_wt(const float* __restrict__ Wk, const float* __restrict__ Wq,
             const float* __restrict__ Wv, ushort_t* __restrict__ WT)
{
    int idx = blockIdx.x * 256 + threadIdx.x;   // 192*1024 total
    int n = idx >> 10;                          // output row (0..191)
    int kk = idx & 1023;
    const float* W = (n < 64) ? Wq : ((n < 128) ? Wk : Wv);
    int h = n & 63;
    WT[idx] = f2bf(W[kk * Hd + h]);
}

// ---------------------------------------------------------------------------
// Projection GEMM v2: block = 16 M-rows, 256 thr (4 waves).
// x tile staged to LDS as bf16 once; wave w computes N-tiles {w, 4+w, 8+w}
// (one tile each of q/k/v). Grid = 1024 -> 4 blocks/CU, 16 waves/CU.
// q written pre-scaled by 1/8 (= Hd^-0.5).
__global__ __launch_bounds__(256)
void proj_mfma(const float* __restrict__ x, const ushort_t* __restrict__ WT,
               ushort_t* __restrict__ qo, ushort_t* __restrict__ ko,
               ushort_t* __restrict__ vo)
{
    // +8 pad -> row stride 516 dwords; 516%32=4 -> only m/m+8 2-way (free)
    __shared__ alignas(16) ushort_t XS[16][1032];

    const int t    = threadIdx.x;
    const int w    = t >> 6;
    const int lane = t & 63;
    const int m    = lane & 15;
    const int g    = lane >> 4;
    const int rb   = blockIdx.x * 16;

    // ---- stage x (16 rows x 1024 fp32 = 64 KB contiguous) -> bf16 LDS
    const float* xbase = x + (size_t)rb * E;
    #pragma unroll
    for (int it = 0; it < 8; ++it) {
        const int f = (it * 256 + t) * 8;        // flat element idx, 8 floats
        float4 xa = *(const float4*)(xbase + f);
        float4 xb = *(const float4*)(xbase + f + 4);
        short8 a;
        a[0] = (short)f2bf(xa.x); a[1] = (short)f2bf(xa.y);
        a[2] = (short)f2bf(xa.z); a[3] = (short)f2bf(xa.w);
        a[4] = (short)f2bf(xb.x); a[5] = (short)f2bf(xb.y);
        a[6] = (short)f2bf(xb.z); a[7] = (short)f2bf(xb.w);
        *(short8*)&XS[f >> 10][f & 1023] = a;
    }
    __syncthreads();

    f32x4 acc[3];
    #pragma unroll
    for (int j = 0; j < 3; ++j) acc[j] = (f32x4){0.f, 0.f, 0.f, 0.f};
    const int nts[3] = {w, 4 + w, 8 + w};

    for (int kt = 0; kt < E / 32; ++kt) {
        const int k0 = kt * 32 + g * 8;
        short8 a = *(const short8*)&XS[m][k0];
        #pragma unroll
        for (int j = 0; j < 3; ++j) {
            short8 b = *(const short8*)(WT + (size_t)(nts[j] * 16 + m) * E + k0);
            acc[j] = __builtin_amdgcn_mfma_f32_16x16x32_bf16(a, b, acc[j], 0, 0, 0);
        }
    }

    // Epilogue: C/D row(M) = g*4+r, col(N) = m (+16*tile)
    const int orow = rb + g * 4;
    const int col  = w * 16 + m;
    #pragma unroll
    for (int r = 0; r < 4; ++r)
        qo[(size_t)(orow + r) * Hd + col] = f2bf(acc[0][r] * 0.125f);
    #pragma unroll
    for (int r = 0; r < 4; ++r)
        ko[(size_t)(orow + r) * Hd + col] = f2bf(acc[1][r]);
    #pragma unroll
    for (int r = 0; r < 4; ++r)
        vo[(size_t)(orow + r) * Hd + col] = f2bf(acc[2][r]);
}

// ---------------------------------------------------------------------------
// Flash attention v2: block = 32 q-rows, 4 waves = 2 q-subtiles x 2 key
// parities. Super-iter s covers 128 keys; parity p takes keys 128s+64p..+63.
// End: merge (m,l,o) of the two parities per subtile through LDS.
// Grid = 512 -> 2 blocks/CU, 8 waves/CU. q is pre-scaled by 1/8.
__global__ __launch_bounds__(256)
void attn_mfma(const ushort_t* __restrict__ q, const ushort_t* __restrict__ k,
               const ushort_t* __restrict__ v, float* __restrict__ out)
{
    const int grow0 = blockIdx.x * 32;       // global q-row base
    const int batch = grow0 >> 11;
    const int qs0   = grow0 & (S - 1);       // seq pos base (32-aligned)
    const ushort_t* kb = k + (size_t)batch * S * Hd;
    const ushort_t* vb = v + (size_t)batch * S * Hd;

    const int t    = threadIdx.x;
    const int w    = t >> 6;
    const int lane = t & 63;
    const int m    = lane & 15;
    const int g    = lane >> 4;
    const int i    = w & 1;                  // q-subtile (16 rows)
    const int p    = w >> 1;                 // key parity half
    const int rowmax = qs0 + i * 16 + 15;

    __shared__ alignas(16) ushort_t VT[Hd][136];    // [h][key 0..127], pad 8
    __shared__ alignas(16) ushort_t PL[4][16][72];  // per-wave P roundtrip
    __shared__ float OB[2][2][16][64];              // [i][p][row][col]
    __shared__ float ML[2][2][16], LL[2][2][16];

    // Q fragments: A[m][kk] = q[grow0+16i+m][kk]
    const ushort_t* qrow = q + (size_t)(grow0 + i * 16 + m) * Hd;
    short8 qf0 = *(const short8*)(qrow + g * 8);
    short8 qf1 = *(const short8*)(qrow + 32 + g * 8);

    f32x4 o[4];
    #pragma unroll
    for (int j = 0; j < 4; ++j) o[j] = (f32x4){0.f, 0.f, 0.f, 0.f};
    float mrun[4] = {-INFINITY, -INFINITY, -INFINITY, -INFINITY};
    float lrun[4] = {0.f, 0.f, 0.f, 0.f};

    const int nsup = ((qs0 + 31) >> 7) + 1;
    for (int s = 0; s < nsup; ++s) {
        const int key0s = s * 128;

        // ---- stage V^T for 128 keys: thread t -> key = t>>1, h-half = t&1
        {
            const int key = t >> 1;
            const int h0  = (t & 1) * 32;
            const int gk  = key0s + key;
            if (gk < S) {
                const ushort_t* vr = vb + (size_t)gk * Hd + h0;
                #pragma unroll
                for (int c = 0; c < 4; ++c) {
                    uint4 u = *(const uint4*)(vr + c * 8);
                    VT[h0 + c*8 + 0][key] = (ushort_t)(u.x & 0xffff);
                    VT[h0 + c*8 + 1][key] = (ushort_t)(u.x >> 16);
                    VT[h0 + c*8 + 2][key] = (ushort_t)(u.y & 0xffff);
                    VT[h0 + c*8 + 3][key] = (ushort_t)(u.y >> 16);
                    VT[h0 + c*8 + 4][key] = (ushort_t)(u.z & 0xffff);
                    VT[h0 + c*8 + 5][key] = (ushort_t)(u.z >> 16);
                    VT[h0 + c*8 + 6][key] = (ushort_t)(u.w & 0xffff);
                    VT[h0 + c*8 + 7][key] = (ushort_t)(u.w >> 16);
                }
            } else {
                #pragma unroll
                for (int c = 0; c < 4; ++c)
                    #pragma unroll
                    for (int j = 0; j < 8; ++j) VT[h0 + c*8 + j][key] = 0;
            }
        }
        __syncthreads();

        const int key0p = key0s + p * 64;
        if (key0p <= rowmax) {
            // ---- S = Q K^T
            f32x4 sacc[4];
            #pragma unroll
            for (int j = 0; j < 4; ++j) sacc[j] = (f32x4){0.f, 0.f, 0.f, 0.f};
            #pragma unroll
            for (int nt = 0; nt < 4; ++nt) {
                const ushort_t* krow = kb + (size_t)(key0p + nt * 16 + m) * Hd;
                short8 b0 = *(const short8*)(krow + g * 8);
                short8 b1 = *(const short8*)(krow + 32 + g * 8);
                sacc[nt] = __builtin_amdgcn_mfma_f32_16x16x32_bf16(qf0, b0, sacc[nt], 0, 0, 0);
                sacc[nt] = __builtin_amdgcn_mfma_f32_16x16x32_bf16(qf1, b1, sacc[nt], 0, 0, 0);
            }

            // ---- causal mask (only near the diagonal)
            if (key0p + 63 > qs0 + i * 16) {
                const int rowg = qs0 + i * 16 + g * 4;
                #pragma unroll
                for (int nt = 0; nt < 4; ++nt) {
                    const int keyg = key0p + nt * 16 + m;
                    #pragma unroll
                    for (int r = 0; r < 4; ++r)
                        if (keyg > rowg + r) sacc[nt][r] = -INFINITY;
                }
            }

            // ---- online softmax (rows live across 16-lane groups)
            float msafe[4], alpha[4];
            #pragma unroll
            for (int r = 0; r < 4; ++r) {
                float tm = fmaxf(fmaxf(sacc[0][r], sacc[1][r]),
                                 fmaxf(sacc[2][r], sacc[3][r]));
                #pragma unroll
                for (int d = 1; d < 16; d <<= 1) tm = fmaxf(tm, __shfl_xor(tm, d, 64));
                float mn = fmaxf(mrun[r], tm);
                msafe[r] = (mn == -INFINITY) ? 0.f : mn;   // guard all-masked tile
                alpha[r] = __expf(mrun[r] - msafe[r]);     // -inf -> 0
                mrun[r]  = mn;
            }
            #pragma unroll
            for (int nt = 0; nt < 4; ++nt)
                #pragma unroll
                for (int r = 0; r < 4; ++r)
                    sacc[nt][r] = __expf(sacc[nt][r] - msafe[r]);
            #pragma unroll
            for (int r = 0; r < 4; ++r) {
                float ts = sacc[0][r] + sacc[1][r] + sacc[2][r] + sacc[3][r];
                #pragma unroll
                for (int d = 1; d < 16; d <<= 1) ts += __shfl_xor(ts, d, 64);
                lrun[r] = lrun[r] * alpha[r] + ts;
            }
            #pragma unroll
            for (int nt = 0; nt < 4; ++nt)
                #pragma unroll
                for (int r = 0; r < 4; ++r)
                    o[nt][r] *= alpha[r];

            // ---- P: C-layout -> per-wave LDS -> A-layout
            #pragma unroll
            for (int nt = 0; nt < 4; ++nt)
                #pragma unroll
                for (int r = 0; r < 4; ++r)
                    PL[w][g * 4 + r][nt * 16 + m] = f2bf(sacc[nt][r]);

            short8 pa0 = *(const short8*)&PL[w][m][g * 8];
            short8 pa1 = *(const short8*)&PL[w][m][32 + g * 8];

            // ---- O += P V (B[n=h][kk=key] = VT[nt*16+m][64p + kk])
            const int vo0 = p * 64;
            #pragma unroll
            for (int nt = 0; nt < 4; ++nt) {
                short8 vb0 = *(const short8*)&VT[nt * 16 + m][vo0 + g * 8];
                short8 vb1 = *(const short8*)&VT[nt * 16 + m][vo0 + 32 + g * 8];
                o[nt] = __builtin_amdgcn_mfma_f32_16x16x32_bf16(pa0, vb0, o[nt], 0, 0, 0);
                o[nt] = __builtin_amdgcn_mfma_f32_16x16x32_bf16(pa1, vb1, o[nt], 0, 0, 0);
            }
        }
        __syncthreads();   // protect VT before next staging
    }

    // ---- cross-parity merge through LDS
    if (m == 0) {
        #pragma unroll
        for (int r = 0; r < 4; ++r) {
            ML[i][p][g * 4 + r] = mrun[r];
            LL[i][p][g * 4 + r] = lrun[r];
        }
    }
    #pragma unroll
    for (int nt = 0; nt < 4; ++nt)
        #pragma unroll
        for (int r = 0; r < 4; ++r)
            OB[i][p][g * 4 + r][nt * 16 + m] = o[nt][r];
    __syncthreads();

    if (p == 0) {
        float a[4], bsc[4], linv[4];
        #pragma unroll
        for (int r = 0; r < 4; ++r) {
            const int rl = g * 4 + r;
            float mA = ML[i][0][rl], mB = ML[i][1][rl];
            float mm = fmaxf(mA, mB);
            float ms = (mm == -INFINITY) ? 0.f : mm;
            a[r]   = __expf(mA - ms);
            bsc[r] = __expf(mB - ms);
            float l = LL[i][0][rl] * a[r] + LL[i][1][rl] * bsc[r];
            linv[r] = 1.f / l;
        }
        #pragma unroll
        for (int nt = 0; nt < 4; ++nt)
            #pragma unroll
            for (int r = 0; r < 4; ++r) {
                const int rl = g * 4 + r, col = nt * 16 + m;
                float oo = OB[i][0][rl][col] * a[r] + OB[i][1][rl][col] * bsc[r];
                out[(size_t)(grow0 + i * 16 + rl) * Hd + col] = oo * linv[r];
            }
    }
}

// ---------------------------------------------------------------------------
extern "C" void kernel_launch(void* const* d_in, const int* in_sizes, int n_in,
                              void* d_out, int out_size, void* d_ws, size_t ws_size,
                              hipStream_t stream) {
    const float* x  = (const float*)d_in[0];
    const float* Wk = (const float*)d_in[1];
    const float* Wq = (const float*)d_in[2];
    const float* Wv = (const float*)d_in[3];
    float* out = (float*)d_out;

    ushort_t* qws = (ushort_t*)d_ws;                       // 16384*64 bf16
    ushort_t* kws = qws + (size_t)ROWS * Hd;
    ushort_t* vws = kws + (size_t)ROWS * Hd;
    ushort_t* WT  = vws + (size_t)ROWS * Hd;               // 192*1024 bf16

    prep_wt<<<(NTOT * E) / 256, 256, 0, stream>>>(Wk, Wq, Wv, WT);
    proj_mfma<<<ROWS / 16, 256, 0, stream>>>(x, WT, qws, kws, vws);
    attn_mfma<<<ROWS / 32, 256, 0, stream>>>(qws, kws, vws, out);
}

// Round 5
// 168.633 us; speedup vs baseline: 7.2868x; 1.1303x over previous
//
#include <hip/hip_runtime.h>
#include <hip/hip_bf16.h>

typedef unsigned short ushort_t;
typedef __attribute__((ext_vector_type(8))) short short8;   // 8 bf16 (4 VGPRs)
typedef __attribute__((ext_vector_type(4))) float f32x4;    // 4 fp32 acc

__device__ __forceinline__ ushort_t f2bf(float f) {
    unsigned int x; __builtin_memcpy(&x, &f, 4);
    x += 0x7fff + ((x >> 16) & 1);
    return (ushort_t)(x >> 16);
}

// async global->LDS, 16B per lane; LDS dest = wave-uniform base + lane*16
__device__ __forceinline__ void gl_lds16(const void* g, void* l) {
    __builtin_amdgcn_global_load_lds(
        (const __attribute__((address_space(1))) void*)g,
        (__attribute__((address_space(3))) void*)l, 16, 0, 0);
}

constexpr int E  = 1024;
constexpr int Hd = 64;
constexpr int S  = 2048;
constexpr int ROWS = 8 * 2048;   // 16384
constexpr int NTOT = 192;        // Q|K|V output columns

// ---------------------------------------------------------------------------
// prep: WT[192][1024] bf16, rows 0-63 = Wq^T, 64-127 = Wk^T, 128-191 = Wv^T
__global__ __launch_bounds__(256)
void prep_wt(const float* __restrict__ Wk, const float* __restrict__ Wq,
             const float* __restrict__ Wv, ushort_t* __restrict__ WT)
{
    int idx = blockIdx.x * 256 + threadIdx.x;   // 192*1024 total
    int n = idx >> 10;                          // output row (0..191)
    int kk = idx & 1023;
    const float* W = (n < 64) ? Wq : ((n < 128) ? Wk : Wv);
    int h = n & 63;
    WT[idx] = f2bf(W[kk * Hd + h]);
}

// ---------------------------------------------------------------------------
// Projection GEMM v3: block = 32 M-rows x 192 N-cols, K-chunk 64, grid 512.
// WT chunk staged via async global_load_lds (contiguous, no pad); x chunk
// converted fp32->bf16 via VGPRs into padded LDS. 4 waves = 2 M-sub x 2 N-half.
// q written pre-scaled by 1/8 (= Hd^-0.5).
__global__ __launch_bounds__(256)
void proj_mfma(const float* __restrict__ x, const ushort_t* __restrict__ WT,
               ushort_t* __restrict__ qo, ushort_t* __restrict__ ko,
               ushort_t* __restrict__ vo)
{
    __shared__ alignas(16) ushort_t WTS[NTOT * 64];   // [n][k], stride 64 (async dest)
    __shared__ alignas(16) ushort_t XS[32][80];       // [m][k], stride 80 (16B-aligned)

    const int t    = threadIdx.x;
    const int w    = t >> 6;
    const int lane = t & 63;
    const int m    = lane & 15;
    const int g    = lane >> 4;
    const int rb   = blockIdx.x * 32;
    const int msub = w & 1;
    const int nh   = w >> 1;

    f32x4 acc[6];
    #pragma unroll
    for (int j = 0; j < 6; ++j) acc[j] = (f32x4){0.f, 0.f, 0.f, 0.f};

    const int xrow = t >> 3;            // 0..31
    const int xc8  = (t & 7) * 8;       // 0..56
    const float* xp0 = x + (size_t)(rb + xrow) * E + xc8;

    for (int c = 0; c < E / 64; ++c) {
        const int k0 = c * 64;

        // ---- stage WT slice [192][64] via async 16B loads (1536 granules)
        #pragma unroll
        for (int it = 0; it < 6; ++it) {
            const int f = it * 256 + t;                    // granule id
            const ushort_t* gp = WT + (size_t)(f >> 3) * E + k0 + (f & 7) * 8;
            // wave-uniform LDS base (lane*16 added by HW)
            gl_lds16(gp, &WTS[(it * 256 + w * 64) * 8]);
        }

        // ---- stage x slice [32][64] fp32 -> bf16 (VGPR round-trip)
        {
            const float* xp = xp0 + k0;
            float4 xa = *(const float4*)xp;
            float4 xb = *(const float4*)(xp + 4);
            short8 a;
            a[0] = (short)f2bf(xa.x); a[1] = (short)f2bf(xa.y);
            a[2] = (short)f2bf(xa.z); a[3] = (short)f2bf(xa.w);
            a[4] = (short)f2bf(xb.x); a[5] = (short)f2bf(xb.y);
            a[6] = (short)f2bf(xb.z); a[7] = (short)f2bf(xb.w);
            *(short8*)&XS[xrow][xc8] = a;
        }
        __syncthreads();   // drains vmcnt (async WT) + lgkm (x writes)

        #pragma unroll
        for (int kt = 0; kt < 2; ++kt) {
            short8 a = *(const short8*)&XS[msub * 16 + m][kt * 32 + g * 8];
            #pragma unroll
            for (int j = 0; j < 6; ++j) {
                const int nt = nh * 6 + j;
                short8 b = *(const short8*)&WTS[(nt * 16 + m) * 64 + kt * 32 + g * 8];
                acc[j] = __builtin_amdgcn_mfma_f32_16x16x32_bf16(a, b, acc[j], 0, 0, 0);
            }
        }
        __syncthreads();
    }

    // ---- epilogue: C/D row(M) = g*4+r, col(N) = m; global col = nh*96+j*16+m
    const int orow = rb + msub * 16 + g * 4;
    #pragma unroll
    for (int j = 0; j < 6; ++j) {
        const int gcol = nh * 96 + j * 16 + m;
        ushort_t* dst; int col; float sc;
        if (gcol < 64)       { dst = qo; col = gcol;       sc = 0.125f; }
        else if (gcol < 128) { dst = ko; col = gcol - 64;  sc = 1.f;    }
        else                 { dst = vo; col = gcol - 128; sc = 1.f;    }
        #pragma unroll
        for (int r = 0; r < 4; ++r)
            dst[(size_t)(orow + r) * Hd + col] = f2bf(acc[j][r] * sc);
    }
}

// ---------------------------------------------------------------------------
// Flash attention v3: block = 32 q-rows, 4 waves = 2 q-subtiles x 2 key
// parities; super-iter covers 128 keys. Work-balance swizzle pairs tile j
// with tile 511-j on the same CU. q is pre-scaled by 1/8.
__global__ __launch_bounds__(256)
void attn_mfma(const ushort_t* __restrict__ q, const ushort_t* __restrict__ k,
               const ushort_t* __restrict__ v, float* __restrict__ out)
{
    const int bi    = blockIdx.x;
    const int qt    = (bi < 256) ? bi : 767 - bi;   // balance: CU gets (c, 511-c)
    const int grow0 = qt * 32;                      // global q-row base
    const int batch = grow0 >> 11;
    const int qs0   = grow0 & (S - 1);              // seq pos base (32-aligned)
    const ushort_t* kb = k + (size_t)batch * S * Hd;
    const ushort_t* vb = v + (size_t)batch * S * Hd;

    const int t    = threadIdx.x;
    const int w    = t >> 6;
    const int lane = t & 63;
    const int m    = lane & 15;
    const int g    = lane >> 4;
    const int i    = w & 1;                  // q-subtile (16 rows)
    const int p    = w >> 1;                 // key parity half
    const int rowmax = qs0 + i * 16 + 15;

    __shared__ alignas(16) ushort_t VT[Hd][136];    // [h][key 0..127], pad 8
    __shared__ alignas(16) ushort_t PL[4][16][72];  // per-wave P roundtrip
    __shared__ float OB[2][2][16][64];              // [i][p][row][col]
    __shared__ float ML[2][2][16], LL[2][2][16];

    // Q fragments: A[m][kk] = q[grow0+16i+m][kk]
    const ushort_t* qrow = q + (size_t)(grow0 + i * 16 + m) * Hd;
    short8 qf0 = *(const short8*)(qrow + g * 8);
    short8 qf1 = *(const short8*)(qrow + 32 + g * 8);

    f32x4 o[4];
    #pragma unroll
    for (int j = 0; j < 4; ++j) o[j] = (f32x4){0.f, 0.f, 0.f, 0.f};
    float mrun[4] = {-INFINITY, -INFINITY, -INFINITY, -INFINITY};
    float lrun[4] = {0.f, 0.f, 0.f, 0.f};

    // V-staging assignment: wave-lane -> (key, h-half); conflict-free writes
    const int skl = (w & 1) * 64 + lane;     // key 0..127
    const int sh0 = (w >> 1) * 32;           // h base

    const int nsup = ((qs0 + 31) >> 7) + 1;
    for (int s = 0; s < nsup; ++s) {
        const int key0s = s * 128;

        // ---- stage V^T for 128 keys (always in-bounds; see nsup bound)
        {
            const ushort_t* vr = vb + (size_t)(key0s + skl) * Hd + sh0;
            #pragma unroll
            for (int c = 0; c < 4; ++c) {
                uint4 u = *(const uint4*)(vr + c * 8);
                // 64 lanes write 64 consecutive key-cols of one h-row: 2-way, free
                VT[sh0 + c*8 + 0][skl] = (ushort_t)(u.x & 0xffff);
                VT[sh0 + c*8 + 1][skl] = (ushort_t)(u.x >> 16);
                VT[sh0 + c*8 + 2][skl] = (ushort_t)(u.y & 0xffff);
                VT[sh0 + c*8 + 3][skl] = (ushort_t)(u.y >> 16);
                VT[sh0 + c*8 + 4][skl] = (ushort_t)(u.z & 0xffff);
                VT[sh0 + c*8 + 5][skl] = (ushort_t)(u.z >> 16);
                VT[sh0 + c*8 + 6][skl] = (ushort_t)(u.w & 0xffff);
                VT[sh0 + c*8 + 7][skl] = (ushort_t)(u.w >> 16);
            }
        }
        __syncthreads();

        const int key0p = key0s + p * 64;
        if (key0p <= rowmax) {
            // ---- S = Q K^T
            f32x4 sacc[4];
            #pragma unroll
            for (int j = 0; j < 4; ++j) sacc[j] = (f32x4){0.f, 0.f, 0.f, 0.f};
            #pragma unroll
            for (int nt = 0; nt < 4; ++nt) {
                const ushort_t* krow = kb + (size_t)(key0p + nt * 16 + m) * Hd;
                short8 b0 = *(const short8*)(krow + g * 8);
                short8 b1 = *(const short8*)(krow + 32 + g * 8);
                sacc[nt] = __builtin_amdgcn_mfma_f32_16x16x32_bf16(qf0, b0, sacc[nt], 0, 0, 0);
                sacc[nt] = __builtin_amdgcn_mfma_f32_16x16x32_bf16(qf1, b1, sacc[nt], 0, 0, 0);
            }

            // ---- causal mask (only near the diagonal)
            if (key0p + 63 > qs0 + i * 16) {
                const int rowg = qs0 + i * 16 + g * 4;
                #pragma unroll
                for (int nt = 0; nt < 4; ++nt) {
                    const int keyg = key0p + nt * 16 + m;
                    #pragma unroll
                    for (int r = 0; r < 4; ++r)
                        if (keyg > rowg + r) sacc[nt][r] = -INFINITY;
                }
            }

            // ---- online softmax (rows live across 16-lane groups)
            float msafe[4], alpha[4];
            #pragma unroll
            for (int r = 0; r < 4; ++r) {
                float tm = fmaxf(fmaxf(sacc[0][r], sacc[1][r]),
                                 fmaxf(sacc[2][r], sacc[3][r]));
                #pragma unroll
                for (int d = 1; d < 16; d <<= 1) tm = fmaxf(tm, __shfl_xor(tm, d, 64));
                float mn = fmaxf(mrun[r], tm);
                msafe[r] = (mn == -INFINITY) ? 0.f : mn;   // guard all-masked tile
                alpha[r] = __expf(mrun[r] - msafe[r]);     // -inf -> 0
                mrun[r]  = mn;
            }
            #pragma unroll
            for (int nt = 0; nt < 4; ++nt)
                #pragma unroll
                for (int r = 0; r < 4; ++r)
                    sacc[nt][r] = __expf(sacc[nt][r] - msafe[r]);
            #pragma unroll
            for (int r = 0; r < 4; ++r) {
                float ts = sacc[0][r] + sacc[1][r] + sacc[2][r] + sacc[3][r];
                #pragma unroll
                for (int d = 1; d < 16; d <<= 1) ts += __shfl_xor(ts, d, 64);
                lrun[r] = lrun[r] * alpha[r] + ts;
            }
            #pragma unroll
            for (int nt = 0; nt < 4; ++nt)
                #pragma unroll
                for (int r = 0; r < 4; ++r)
                    o[nt][r] *= alpha[r];

            // ---- P: C-layout -> per-wave LDS -> A-layout
            #pragma unroll
            for (int nt = 0; nt < 4; ++nt)
                #pragma unroll
                for (int r = 0; r < 4; ++r)
                    PL[w][g * 4 + r][nt * 16 + m] = f2bf(sacc[nt][r]);

            short8 pa0 = *(const short8*)&PL[w][m][g * 8];
            short8 pa1 = *(const short8*)&PL[w][m][32 + g * 8];

            // ---- O += P V (B[n=h][kk=key] = VT[nt*16+m][64p + kk])
            const int vo0 = p * 64;
            #pragma unroll
            for (int nt = 0; nt < 4; ++nt) {
                short8 vb0 = *(const short8*)&VT[nt * 16 + m][vo0 + g * 8];
                short8 vb1 = *(const short8*)&VT[nt * 16 + m][vo0 + 32 + g * 8];
                o[nt] = __builtin_amdgcn_mfma_f32_16x16x32_bf16(pa0, vb0, o[nt], 0, 0, 0);
                o[nt] = __builtin_amdgcn_mfma_f32_16x16x32_bf16(pa1, vb1, o[nt], 0, 0, 0);
            }
        }
        __syncthreads();   // protect VT before next staging
    }

    // ---- cross-parity merge through LDS
    if (m == 0) {
        #pragma unroll
        for (int r = 0; r < 4; ++r) {
            ML[i][p][g * 4 + r] = mrun[r];
            LL[i][p][g * 4 + r] = lrun[r];
        }
    }
    #pragma unroll
    for (int nt = 0; nt < 4; ++nt)
        #pragma unroll
        for (int r = 0; r < 4; ++r)
            OB[i][p][g * 4 + r][nt * 16 + m] = o[nt][r];
    __syncthreads();

    if (p == 0) {
        float a[4], bsc[4], linv[4];
        #pragma unroll
        for (int r = 0; r < 4; ++r) {
            const int rl = g * 4 + r;
            float mA = ML[i][0][rl], mB = ML[i][1][rl];
            float mm = fmaxf(mA, mB);
            float ms = (mm == -INFINITY) ? 0.f : mm;
            a[r]   = __expf(mA - ms);
            bsc[r] = __expf(mB - ms);
            float l = LL[i][0][rl] * a[r] + LL[i][1][rl] * bsc[r];
            linv[r] = 1.f / l;
        }
        #pragma unroll
        for (int nt = 0; nt < 4; ++nt)
            #pragma unroll
            for (int r = 0; r < 4; ++r) {
                const int rl = g * 4 + r, col = nt * 16 + m;
                float oo = OB[i][0][rl][col] * a[r] + OB[i][1][rl][col] * bsc[r];
                out[(size_t)(grow0 + i * 16 + rl) * Hd + col] = oo * linv[r];
            }
    }
}

// ---------------------------------------------------------------------------
extern "C" void kernel_launch(void* const* d_in, const int* in_sizes, int n_in,
                              void* d_out, int out_size, void* d_ws, size_t ws_size,
                              hipStream_t stream) {
    const float* x  = (const float*)d_in[0];
    const float* Wk = (const float*)d_in[1];
    const float* Wq = (const float*)d_in[2];
    const float* Wv = (const float*)d_in[3];
    float* out = (float*)d_out;

    ushort_t* qws = (ushort_t*)d_ws;                       // 16384*64 bf16
    ushort_t* kws = qws + (size_t)ROWS * Hd;
    ushort_t* vws = kws + (size_t)ROWS * Hd;
    ushort_t* WT  = vws + (size_t)ROWS * Hd;               // 192*1024 bf16

    prep_wt<<<(NTOT * E) / 256, 256, 0, stream>>>(Wk, Wq, Wv, WT);
    proj_mfma<<<ROWS / 32, 256, 0, stream>>>(x, WT, qws, kws, vws);
    attn_mfma<<<ROWS / 32, 256, 0, stream>>>(qws, kws, vws, out);
}